// Round 3
// baseline (7274.559 us; speedup 1.0000x reference)
//
#include <hip/hip_runtime.h>
#include <stdint.h>

#define T_SEQ 1024
#define BATCH 32
#define HID   512
#define RING  32     // all inter-stage rings: 32 steps deep (power of 2)

typedef unsigned short u16;
typedef unsigned long long u64;
typedef short bf16x8 __attribute__((ext_vector_type(8)));
typedef float f32x4  __attribute__((ext_vector_type(4)));
typedef unsigned int u32x4 __attribute__((ext_vector_type(4)));

__device__ __forceinline__ float bf2f(u16 u) {
  union { unsigned u; float f; } v; v.u = ((unsigned)u) << 16; return v.f;
}
__device__ __forceinline__ u16 f2bf(float f) {
  union { float f; unsigned u; } v; v.f = f;
  unsigned r = v.u + 0x7fffu + ((v.u >> 16) & 1u);   // RNE
  return (u16)(r >> 16);
}
__device__ __forceinline__ float sigf(float x) { return 1.0f / (1.0f + __expf(-x)); }
__device__ __forceinline__ float tanh_fast(float x) { return 2.0f * sigf(2.0f * x) - 1.0f; }

// Device-scope coherent stores/loads for tags + ring publishes.
__device__ __forceinline__ void st_dev(u64* p, u64 v) {
  __hip_atomic_store(p, v, __ATOMIC_RELAXED, __HIP_MEMORY_SCOPE_AGENT);
}
__device__ __forceinline__ void st_tag(int* p, int v) {
  __hip_atomic_store(p, v, __ATOMIC_RELAXED, __HIP_MEMORY_SCOPE_AGENT);
}
__device__ __forceinline__ int ld_flag(const int* p) {
  return __hip_atomic_load(p, __ATOMIC_RELAXED, __HIP_MEMORY_SCOPE_AGENT);
}

// Coherent 16B load/store: sc0 sc1 bypass L1 + per-XCD L2 (read/write the
// cross-XCD coherence point). Hazard tracking manual (s_waitcnt + sched_barrier).
#define GLD16(dst, p, OFS) \
  asm volatile("global_load_dwordx4 %0, %1, off offset:" OFS " sc0 sc1" \
               : "=v"(dst) : "v"(p) : "memory")
#define GST16(p, val, OFS) \
  asm volatile("global_store_dwordx4 %0, %1, off offset:" OFS " sc0 sc1" \
               :: "v"(p), "v"(val) : "memory")

// 16 named 16B registers (64 VGPRs) so SROA keeps everything in registers.
struct Frag {
  u32x4 d0,d1,d2,d3,d4,d5,d6,d7,d8,d9,d10,d11,d12,d13,d14,d15;
};

__device__ __forceinline__ void issue_frag(const u16* p, Frag& f) {
  GLD16(f.d0,  p, "0");   GLD16(f.d1,  p, "64");
  GLD16(f.d2,  p, "128"); GLD16(f.d3,  p, "192");
  GLD16(f.d4,  p, "256"); GLD16(f.d5,  p, "320");
  GLD16(f.d6,  p, "384"); GLD16(f.d7,  p, "448");
  GLD16(f.d8,  p, "512"); GLD16(f.d9,  p, "576");
  GLD16(f.d10, p, "640"); GLD16(f.d11, p, "704");
  GLD16(f.d12, p, "768"); GLD16(f.d13, p, "832");
  GLD16(f.d14, p, "896"); GLD16(f.d15, p, "960");
}

// K=512 16x16x32 MFMA chain over a pre-loaded fragment.
__device__ __forceinline__ f32x4 frag_compute(const Frag& f, const u16 (*w)[520],
                                              int wrow, int kq) {
  f32x4 z = {0.f,0.f,0.f,0.f};
  f32x4 a[4] = {z, z, z, z};
#define FSTEP(ii, dd) { union { u32x4 q; bf16x8 v; } c; c.q = f.dd; \
  bf16x8 bv = *reinterpret_cast<const bf16x8*>(&w[wrow][kq + ii * 32]); \
  a[ii & 3] = __builtin_amdgcn_mfma_f32_16x16x32_bf16(c.v, bv, a[ii & 3], 0, 0, 0); }
  FSTEP(0,d0)   FSTEP(1,d1)   FSTEP(2,d2)   FSTEP(3,d3)
  FSTEP(4,d4)   FSTEP(5,d5)   FSTEP(6,d6)   FSTEP(7,d7)
  FSTEP(8,d8)   FSTEP(9,d9)   FSTEP(10,d10) FSTEP(11,d11)
  FSTEP(12,d12) FSTEP(13,d13) FSTEP(14,d14) FSTEP(15,d15)
#undef FSTEP
  return (a[0] + a[1]) + (a[2] + a[3]);
}

// Min of consumer-progress flags across the wave (lanes >= n contribute MAX).
__device__ __forceinline__ int poll_min(const int* base, int n, int lane) {
  int f = 0x7fffffff;
  if (lane < n) f = ld_flag(&base[lane]);
#pragma unroll
  for (int off = 32; off >= 1; off >>= 1) {
    int o = __shfl_xor(f, off);
    f = o < f ? o : f;
  }
  return f;
}

// Tag helpers: tag array layout = int tag[RING][64*4]; entry (slot, j) at
// slot*256 + j*4 (16B spread to dilute line hotness).
__device__ __forceinline__ int tag_idx(int slot, int j) { return slot * 256 + j * 4; }

// ---------------- cast fp32 -> bf16 ----------------
__global__ __launch_bounds__(256) void cast_f32_bf16(const float* __restrict__ in,
                                                     u16* __restrict__ out, int n) {
  int i = (blockIdx.x * 256 + threadIdx.x) * 8;
  if (i + 7 < n) {
    float4 v0 = *reinterpret_cast<const float4*>(in + i);
    float4 v1 = *reinterpret_cast<const float4*>(in + i + 4);
    uint4 o;
    o.x = (unsigned)f2bf(v0.x) | ((unsigned)f2bf(v0.y) << 16);
    o.y = (unsigned)f2bf(v0.z) | ((unsigned)f2bf(v0.w) << 16);
    o.z = (unsigned)f2bf(v1.x) | ((unsigned)f2bf(v1.y) << 16);
    o.w = (unsigned)f2bf(v1.z) | ((unsigned)f2bf(v1.w) << 16);
    *reinterpret_cast<uint4*>(out + i) = o;
  } else {
    for (; i < n; ++i) out[i] = f2bf(in[i]);
  }
}

// ---------------- LSTM input GEMM: out[t][b][k][g] = x @ w_ih^T + b_ih + b_hh ----------------
__global__ __launch_bounds__(256) void gemm_xg(
    const u16* __restrict__ A, const u16* __restrict__ W,
    const float* __restrict__ bias1, const float* __restrict__ bias2,
    u16* __restrict__ out, int N, int K, int strideB, int strideT)
{
  __shared__ u16 As[64][72];
  __shared__ u16 Bs[64][72];
  int tid  = threadIdx.x;
  int lane = tid & 63;
  int wave = tid >> 6;
  int m0 = blockIdx.x * 64;
  int n0 = blockIdx.y * 64;

  f32x4 zero = {0.f, 0.f, 0.f, 0.f};
  f32x4 acc[4] = {zero, zero, zero, zero};

  int srow = tid >> 2;
  int scol = (tid & 3) * 16;

  int m_s = m0 + srow;
  long arow = (long)(m_s & (BATCH - 1)) * strideB + (long)(m_s >> 5) * strideT;
  const u16* aptr = A + arow * K + scol;
  const u16* wptr = W + (long)(n0 + srow) * K + scol;

  for (int kk = 0; kk < K; kk += 64) {
    __syncthreads();
    uint4 a0 = *reinterpret_cast<const uint4*>(aptr + kk);
    uint4 a1 = *reinterpret_cast<const uint4*>(aptr + kk + 8);
    uint4 b0 = *reinterpret_cast<const uint4*>(wptr + kk);
    uint4 b1 = *reinterpret_cast<const uint4*>(wptr + kk + 8);
    *reinterpret_cast<uint4*>(&As[srow][scol])     = a0;
    *reinterpret_cast<uint4*>(&As[srow][scol + 8]) = a1;
    *reinterpret_cast<uint4*>(&Bs[srow][scol])     = b0;
    *reinterpret_cast<uint4*>(&Bs[srow][scol + 8]) = b1;
    __syncthreads();
    int am = wave * 16 + (lane & 15);
    int kq = (lane >> 4) * 8;
#pragma unroll
    for (int ks = 0; ks < 2; ++ks) {
      bf16x8 af = *reinterpret_cast<const bf16x8*>(&As[am][kq + ks * 32]);
#pragma unroll
      for (int nb = 0; nb < 4; ++nb) {
        bf16x8 bf = *reinterpret_cast<const bf16x8*>(&Bs[nb * 16 + (lane & 15)][kq + ks * 32]);
        acc[nb] = __builtin_amdgcn_mfma_f32_16x16x32_bf16(af, bf, acc[nb], 0, 0, 0);
      }
    }
  }
  int quad = lane >> 4;
#pragma unroll
  for (int nb = 0; nb < 4; ++nb) {
    int n = n0 + nb * 16 + (lane & 15);
    float bv = bias1[n] + (bias2 ? bias2[n] : 0.0f);
    int g = n >> 9, k = n & 511;
#pragma unroll
    for (int r = 0; r < 4; ++r) {
      int m = m0 + wave * 16 + quad * 4 + r;
      int t = m >> 5, b = m & (BATCH - 1);
      out[(((long)t * BATCH + b) * HID + k) * 4 + g] = f2bf(acc[nb][r] + bv);
    }
  }
}

// ---------------- persistent recurrent role (ROLE: 0=LSTM 1=GRU 2=RNN) ----------------
// Sequenced-tag protocol: producer j of ring slot s publishes data, waits the
// store ack (vmcnt(0)), then stores tag[s][j] = t+1. Consumers spin on 4B tags
// only (tiny fabric traffic), then bulk-load fragments exactly once.
template <int ROLE>
__device__ void recur_role(
    int wg, const u16* __restrict__ xg, const u16* __restrict__ up,
    const u16* __restrict__ wih, const u16* __restrict__ whh,
    const float* __restrict__ bih, const float* __restrict__ bhh,
    u16* __restrict__ hist,
    const int* tag_up, int n_up, int* tag_own,
    int* fl_own, const int* cons, int n_cons,
    u16 (*w_lds)[520], float (*gx)[33], float (*gh)[33], u16 (*hs)[8])
{
  constexpr int NG = (ROLE == 0) ? 4 : (ROLE == 1) ? 3 : 1;
  constexpr int NPAD = (ROLE == 2) ? 16 : 32;
  constexpr int XROWS = (ROLE > 0) ? NG * 8 : 0;   // x-weight rows staged
  constexpr int TOT = XROWS + NG * 8;
  int tid = threadIdx.x, lane = tid & 63, wave = tid >> 6;
  int hbase = wg * 8;

  // stage weights compactly: rows [0,XROWS) = w_ih slice, [XROWS,TOT) = w_hh slice
  for (int idx = tid; idx < TOT * 64; idx += 256) {
    int row = idx >> 6, chunk = idx & 63;
    int n = (row < XROWS) ? row : (row - XROWS);
    const u16* src = (row < XROWS) ? wih : whh;
    int g = n >> 3, dd = n & 7;
    uint4 v = *reinterpret_cast<const uint4*>(src + ((long)(g * 512 + hbase + dd)) * 512 + chunk * 8);
    *reinterpret_cast<uint4*>(&w_lds[row][chunk * 8]) = v;
  }
  __syncthreads();

  int mt = wave & 1, nt = wave >> 1;
  bool mact = (nt * 16) < NPAD;
  int colw = nt * 16 + (lane & 15);
  int wr = (colw < NG * 8) ? colw : (NG * 8 - 1);   // clamped B row (cols>=NG*8 unused)
  int arow = mt * 16 + (lane & 15);
  int kq = (lane >> 4) * 8;
  float bxw = 0.f, bhw = 0.f;
  if (colw < NG * 8) {
    int g = colw >> 3, dd = colw & 7;
    if constexpr (ROLE == 1) { bxw = bih[g * 512 + hbase + dd]; bhw = bhh[g * 512 + hbase + dd]; }
    if constexpr (ROLE == 2) { bxw = bih[hbase + dd] + bhh[hbase + dd]; }
    (void)g;
  }
  int b_c = tid >> 3, d_c = tid & 7;   // cell thread owns h[b_c][hbase+d_c]
  float c_st = 0.f, h_st = 0.f;
  int ccache = 0;                      // cached min of consumer progress

  for (int t = 0; t < T_SEQ; ++t) {
    u64 xq = 0;
    if constexpr (ROLE == 0)
      xq = *reinterpret_cast<const u64*>(xg + (((long)t * BATCH + b_c) * HID + hbase + d_c) * 4);

    f32x4 aX = {0.f,0.f,0.f,0.f}, aH = {0.f,0.f,0.f,0.f};
    if (mact) {
      // --- wave0: amortized back-pressure gate (own-ring slot overwrite) ---
      if (wave == 0 && cons != nullptr && t >= RING) {
        int need = t - RING + 1;     // downstream consumed step t-RING
        while (ccache < need) {
          ccache = poll_min(cons, n_cons, lane);
          if (ccache < need) __builtin_amdgcn_s_sleep(8);
        }
      }
      // --- spin on 4B sequenced tags (cheap), then load fragments once ---
      if (ROLE > 0 || t > 0) {
        while (true) {
          bool ok = true;
          if constexpr (ROLE > 0) {
            int v1 = (lane < n_up)
                   ? ld_flag(tag_up + tag_idx(t & (RING - 1), lane)) : (t + 1);
            ok &= (v1 == t + 1);
          }
          if (t > 0) {
            int v2 = ld_flag(tag_own + tag_idx((t - 1) & (RING - 1), lane));
            ok &= (v2 == t);
          }
          if (__all(ok)) break;
          __builtin_amdgcn_s_sleep(1);
        }
        __asm__ volatile("" ::: "memory");
      }
      Frag fX, fH;
      if constexpr (ROLE > 0)
        issue_frag(up + ((long)(t & (RING - 1)) * BATCH + arow) * HID + kq, fX);
      if (t > 0)
        issue_frag(hist + ((long)((t - 1) & (RING - 1)) * BATCH + arow) * HID + kq, fH);

      if constexpr (ROLE > 0) {
        // fX = 16 oldest outstanding loads: vmcnt(16) releases them while fH
        // still flies -> aX MFMAs overlap the aH load latency.
        if (t > 0) asm volatile("s_waitcnt vmcnt(16)" ::: "memory");
        else       asm volatile("s_waitcnt vmcnt(0)"  ::: "memory");
        __builtin_amdgcn_sched_barrier(0);
        aX = frag_compute(fX, w_lds, wr, kq);
      }
      if (t > 0) {
        asm volatile("s_waitcnt vmcnt(0)" ::: "memory");
        __builtin_amdgcn_sched_barrier(0);
        aH = frag_compute(fH, w_lds + XROWS, wr, kq);
      }
      int quad = lane >> 4;
#pragma unroll
      for (int r = 0; r < 4; ++r) {
        int row = mt * 16 + quad * 4 + r;
        gx[row][colw] = aX[r] + bxw;
        gh[row][colw] = aH[r] + bhw;
      }
    }
    __syncthreads();

    float hnew;
    if constexpr (ROLE == 0) {
      float xv0 = bf2f((u16)(xq));
      float xv1 = bf2f((u16)(xq >> 16));
      float xv2 = bf2f((u16)(xq >> 32));
      float xv3 = bf2f((u16)(xq >> 48));
      float h0 = gh[b_c][0 * 8 + d_c];
      float h1 = gh[b_c][1 * 8 + d_c];
      float h2 = gh[b_c][2 * 8 + d_c];
      float h3 = gh[b_c][3 * 8 + d_c];
      float ig = sigf(xv0 + h0), fg = sigf(xv1 + h1);
      float gg = tanh_fast(xv2 + h2), og = sigf(xv3 + h3);
      c_st = fg * c_st + ig * gg;
      hnew = og * tanh_fast(c_st);
    } else if constexpr (ROLE == 1) {
      float xr_ = gx[b_c][0 * 8 + d_c], xz = gx[b_c][1 * 8 + d_c], xn = gx[b_c][2 * 8 + d_c];
      float hr  = gh[b_c][0 * 8 + d_c], hz = gh[b_c][1 * 8 + d_c], hn = gh[b_c][2 * 8 + d_c];
      float r = sigf(xr_ + hr), z = sigf(xz + hz);
      float n = tanh_fast(xn + r * hn);
      hnew = (1.f - z) * n + z * h_st;
      h_st = hnew;
    } else {
      hnew = tanh_fast(gx[b_c][d_c] + gh[b_c][d_c]);
    }
    hs[b_c][d_c] = f2bf(hnew);
    __syncthreads();

    if (wave == 0) {
      int pb = lane >> 1, half = lane & 1;
      u64 val = *reinterpret_cast<const u64*>(&hs[pb][half * 4]);
      st_dev(reinterpret_cast<u64*>(
                 hist + (((long)(t & (RING - 1)) * BATCH + pb) * HID + hbase + half * 4)),
             val);
      // ack = data committed at the coherence point, THEN publish the tag
      asm volatile("s_waitcnt vmcnt(0)" ::: "memory");
      if (tid == 0) {
        st_tag(tag_own + tag_idx(t & (RING - 1), wg), t + 1);
        if (fl_own != nullptr) st_tag(&fl_own[wg], t + 1);
      }
    }
  }
}

// ---------------- pipelined LayerNorm role (4 WGs x 8 rows) ----------------
__device__ void ln_role(int wg, const u16* __restrict__ in, u16* __restrict__ out,
                        const float* __restrict__ gv, const float* __restrict__ bv,
                        const int* tag_in, int* tag_out, int* fl_out,
                        const int* cons, int n_cons)
{
  int tid = threadIdx.x, lane = tid & 63, wave = tid >> 6;
  int row = wg * 8 + wave * 2 + (lane >> 5);
  int l32 = lane & 31, k0 = l32 * 16;
  float gr[16], br[16];
#pragma unroll
  for (int j = 0; j < 16; ++j) { gr[j] = gv[k0 + j]; br[j] = bv[k0 + j]; }
  int ccache = 0;

  for (int t = 0; t < T_SEQ; ++t) {
    // back-pressure gate: downstream consumed step t-RING before we overwrite
    if (t >= RING) {
      int need = t - RING + 1;
      while (ccache < need) {
        ccache = poll_min(cons, n_cons, lane);
        if (ccache < need) __builtin_amdgcn_s_sleep(8);
      }
    }
    // spin on input tags (64 producers)
    while (true) {
      int v = ld_flag(tag_in + tag_idx(t & (RING - 1), lane));
      if (__all(v == t + 1)) break;
      __builtin_amdgcn_s_sleep(1);
    }
    __asm__ volatile("" ::: "memory");

    const u16* p = in + ((long)(t & (RING - 1)) * BATCH + row) * HID + k0;
    u32x4 q0, q1;
    GLD16(q0, p, "0");
    GLD16(q1, p, "16");
    asm volatile("s_waitcnt vmcnt(0)" ::: "memory");
    __builtin_amdgcn_sched_barrier(0);
    union { u32x4 q; u16 s[8]; } u0, u1;
    u0.q = q0; u1.q = q1;
    float x[16];
#pragma unroll
    for (int i = 0; i < 8; ++i) { x[i] = bf2f(u0.s[i]); x[8 + i] = bf2f(u1.s[i]); }
    float s = 0.f, s2 = 0.f;
#pragma unroll
    for (int i = 0; i < 16; ++i) { s += x[i]; s2 += x[i] * x[i]; }
#pragma unroll
    for (int off = 1; off < 32; off <<= 1) { s += __shfl_xor(s, off); s2 += __shfl_xor(s2, off); }
    float mu = s * (1.f / 512.f);
    float var = s2 * (1.f / 512.f) - mu * mu;
    float rs = rsqrtf(var + 1e-5f);
    union { u16 o[16]; u32x4 q[2]; } ov;
#pragma unroll
    for (int i = 0; i < 16; ++i) ov.o[i] = f2bf((x[i] - mu) * rs * gr[i] + br[i]);
    u16* po = out + ((long)(t & (RING - 1)) * BATCH + row) * HID + k0;
    GST16(po, ov.q[0], "0");
    GST16(po, ov.q[1], "16");
    // ack all stores of this WG, then tag
    asm volatile("s_waitcnt vmcnt(0)" ::: "memory");
    __syncthreads();
    if (tid == 0) {
      st_tag(tag_out + tag_idx(t & (RING - 1), wg), t + 1);
      st_tag(&fl_out[wg], t + 1);
    }
  }
}

// ---------------- fused pipeline kernel: 200 WGs ----------------
// flags (back-pressure only): [64..67] ln1, [128..191] gru, [192..195] ln2,
// [256..319] rnn.  tags: per-ring [RING][64*4] int arrays.
__global__ __launch_bounds__(256, 1) void fused_kernel(
    const u16* __restrict__ xg, const u16* __restrict__ lstm_whh,
    const u16* __restrict__ gru_wih, const u16* __restrict__ gru_whh,
    const float* __restrict__ gru_bih, const float* __restrict__ gru_bhh,
    const u16* __restrict__ rnn_wih, const u16* __restrict__ rnn_whh,
    const float* __restrict__ rnn_bih, const float* __restrict__ rnn_bhh,
    const float* __restrict__ ln1_g, const float* __restrict__ ln1_b,
    const float* __restrict__ ln2_g, const float* __restrict__ ln2_b,
    u16* h1, u16* ln1o, u16* h2, u16* ln2o, u16* h3, int* fl, int* tags)
{
  __shared__ u16 w_lds[48][520];     // 49.9 KB  (total static LDS 58.9 KB < 64 KB)
  __shared__ float gx[32][33];       // 4.2 KB
  __shared__ float gh[32][33];       // 4.2 KB
  __shared__ u16 hs[32][8];          // 0.5 KB
  int* tagH1 = tags + 0 * RING * 256;
  int* tagL1 = tags + 1 * RING * 256;
  int* tagH2 = tags + 2 * RING * 256;
  int* tagL2 = tags + 3 * RING * 256;
  int* tagH3 = tags + 4 * RING * 256;
  int bid = blockIdx.x;
  if (bid < 64)
    recur_role<0>(bid, xg, nullptr, nullptr, lstm_whh, nullptr, nullptr,
                  h1, nullptr, 0, tagH1, nullptr, fl + 64, 4,
                  w_lds, gx, gh, hs);
  else if (bid < 68)
    ln_role(bid - 64, h1, ln1o, ln1_g, ln1_b, tagH1, tagL1, fl + 64, fl + 128, 64);
  else if (bid < 132)
    recur_role<1>(bid - 68, nullptr, ln1o, gru_wih, gru_whh, gru_bih, gru_bhh,
                  h2, tagL1, 4, tagH2, fl + 128, fl + 192, 4,
                  w_lds, gx, gh, hs);
  else if (bid < 136)
    ln_role(bid - 132, h2, ln2o, ln2_g, ln2_b, tagH2, tagL2, fl + 192, fl + 256, 64);
  else
    recur_role<2>(bid - 136, nullptr, ln2o, rnn_wih, rnn_whh, rnn_bih, rnn_bhh,
                  h3, tagL2, 4, tagH3, fl + 256, nullptr, 0,
                  w_lds, gx, gh, hs);
}

// ---------------- final FC ----------------
__global__ __launch_bounds__(256) void fc_kernel(
    const u16* __restrict__ hlast, const u16* __restrict__ w,
    const float* __restrict__ bias, float* __restrict__ out)
{
  int tg = blockIdx.x * 256 + threadIdx.x;
  if (tg >= BATCH * 1000) return;
  int b = tg / 1000, o = tg % 1000;
  const u16* hp = hlast + (long)b * HID;
  const u16* wp = w + (long)o * HID;
  float acc = 0.f;
  for (int k = 0; k < HID; k += 8) {
    uint4 hu = *reinterpret_cast<const uint4*>(hp + k);
    uint4 wu = *reinterpret_cast<const uint4*>(wp + k);
    u16* hsv = reinterpret_cast<u16*>(&hu);
    u16* wsv = reinterpret_cast<u16*>(&wu);
#pragma unroll
    for (int i = 0; i < 8; ++i) acc += bf2f(hsv[i]) * bf2f(wsv[i]);
  }
  out[tg] = acc + bias[o];
}

__global__ void sentinel_kernel(float* out) { out[0] = 12345.0f; }

// ---------------- launch ----------------
extern "C" void kernel_launch(void* const* d_in, const int* in_sizes, int n_in,
                              void* d_out, int out_size, void* d_ws, size_t ws_size,
                              hipStream_t stream)
{
  (void)in_sizes; (void)n_in; (void)out_size;
  const float* x        = (const float*)d_in[0];
  const float* lstm_wih = (const float*)d_in[1];
  const float* lstm_whh = (const float*)d_in[2];
  const float* lstm_bih = (const float*)d_in[3];
  const float* lstm_bhh = (const float*)d_in[4];
  const float* ln1_g    = (const float*)d_in[5];
  const float* ln1_b    = (const float*)d_in[6];
  const float* gru_wih  = (const float*)d_in[7];
  const float* gru_whh  = (const float*)d_in[8];
  const float* gru_bih  = (const float*)d_in[9];
  const float* gru_bhh  = (const float*)d_in[10];
  const float* ln2_g    = (const float*)d_in[11];
  const float* ln2_b    = (const float*)d_in[12];
  const float* rnn_wih  = (const float*)d_in[13];
  const float* rnn_whh  = (const float*)d_in[14];
  const float* rnn_bih  = (const float*)d_in[15];
  const float* rnn_bhh  = (const float*)d_in[16];
  const float* fc_w     = (const float*)d_in[17];
  const float* fc_b     = (const float*)d_in[18];
  float* out = (float*)d_out;

  char* ws = (char*)d_ws;
  size_t off = 0;
  auto alloc = [&](size_t bytes) -> void* {
    void* p = ws + off; off += (bytes + 255) & ~(size_t)255; return p;
  };
  int* flags     = (int*)alloc(320 * sizeof(int));
  int* tags      = (int*)alloc((size_t)5 * RING * 256 * sizeof(int));  // 160 KB
  u16* xbf       = (u16*)alloc((size_t)BATCH * T_SEQ * 256 * 2);
  u16* lstm_wih_b= (u16*)alloc((size_t)2048 * 256 * 2);
  u16* lstm_whh_b= (u16*)alloc((size_t)2048 * 512 * 2);
  u16* gru_wih_b = (u16*)alloc((size_t)1536 * 512 * 2);
  u16* gru_whh_b = (u16*)alloc((size_t)1536 * 512 * 2);
  u16* rnn_wih_b = (u16*)alloc((size_t)512 * 512 * 2);
  u16* rnn_whh_b = (u16*)alloc((size_t)512 * 512 * 2);
  u16* fc_w_b    = (u16*)alloc((size_t)1000 * 512 * 2);
  u16* xg2       = (u16*)alloc((size_t)T_SEQ * BATCH * HID * 4 * 2);  // 128 MB
  u16* h1        = (u16*)alloc((size_t)RING * BATCH * HID * 2);       // 1 MB rings
  u16* ln1o      = (u16*)alloc((size_t)RING * BATCH * HID * 2);
  u16* h2        = (u16*)alloc((size_t)RING * BATCH * HID * 2);
  u16* ln2o      = (u16*)alloc((size_t)RING * BATCH * HID * 2);
  u16* h3        = (u16*)alloc((size_t)RING * BATCH * HID * 2);

  if (off > ws_size) {
    sentinel_kernel<<<1, 1, 0, stream>>>(out);
    return;
  }

  hipMemsetAsync(flags, 0, 320 * sizeof(int), stream);
  hipMemsetAsync(tags, 0, (size_t)5 * RING * 256 * sizeof(int), stream);

  auto cast = [&](const float* src, u16* dst, int n) {
    cast_f32_bf16<<<(n + 2047) / 2048, 256, 0, stream>>>(src, dst, n);
  };
  cast(x,        xbf,        BATCH * T_SEQ * 256);
  cast(lstm_wih, lstm_wih_b, 2048 * 256);
  cast(lstm_whh, lstm_whh_b, 2048 * 512);
  cast(gru_wih,  gru_wih_b,  1536 * 512);
  cast(gru_whh,  gru_whh_b,  1536 * 512);
  cast(rnn_wih,  rnn_wih_b,  512 * 512);
  cast(rnn_whh,  rnn_whh_b,  512 * 512);
  cast(fc_w,     fc_w_b,     1000 * 512);

  const int M64 = (BATCH * T_SEQ) / 64;  // 512
  gemm_xg<<<dim3(M64, 2048 / 64), 256, 0, stream>>>(
      xbf, lstm_wih_b, lstm_bih, lstm_bhh, xg2, 2048, 256, 1024, 1);

  fused_kernel<<<200, 256, 0, stream>>>(
      xg2, lstm_whh_b,
      gru_wih_b, gru_whh_b, gru_bih, gru_bhh,
      rnn_wih_b, rnn_whh_b, rnn_bih, rnn_bhh,
      ln1_g, ln1_b, ln2_g, ln2_b,
      h1, ln1o, h2, ln2o, h3, flags, tags);

  // h3 last written slot = (T_SEQ-1)&31 = 31
  fc_kernel<<<(BATCH * 1000 + 255) / 256, 256, 0, stream>>>(
      h3 + (size_t)31 * BATCH * HID, fc_w_b, fc_b, out);
}

// Round 5
// 6273.042 us; speedup vs baseline: 1.1597x; 1.1597x over previous
//
#include <hip/hip_runtime.h>
#include <stdint.h>

#define T_SEQ 1024
#define BATCH 32
#define HID   512
#define RING  32     // all inter-stage rings: 32 steps deep (power of 2)

typedef unsigned short u16;
typedef unsigned long long u64;
typedef short bf16x8 __attribute__((ext_vector_type(8)));
typedef float f32x4  __attribute__((ext_vector_type(4)));
typedef unsigned int u32x4 __attribute__((ext_vector_type(4)));

// bf16 NaN pattern: unreachable for real ring data (all payloads finite).
#define CAN64 0x7FC07FC07FC07FC0ull

__device__ __forceinline__ float bf2f(u16 u) {
  union { unsigned u; float f; } v; v.u = ((unsigned)u) << 16; return v.f;
}
__device__ __forceinline__ u16 f2bf(float f) {
  union { float f; unsigned u; } v; v.f = f;
  unsigned r = v.u + 0x7fffu + ((v.u >> 16) & 1u);   // RNE
  return (u16)(r >> 16);
}
__device__ __forceinline__ float sigf(float x) { return 1.0f / (1.0f + __expf(-x)); }
__device__ __forceinline__ float tanh_fast(float x) { return 2.0f * sigf(2.0f * x) - 1.0f; }

// Device-scope coherent publish + progress flags.
__device__ __forceinline__ void st_dev(u64* p, u64 v) {
  __hip_atomic_store(p, v, __ATOMIC_RELAXED, __HIP_MEMORY_SCOPE_AGENT);
}
__device__ __forceinline__ void st_tag(int* p, int v) {
  __hip_atomic_store(p, v, __ATOMIC_RELAXED, __HIP_MEMORY_SCOPE_AGENT);
}
__device__ __forceinline__ int ld_flag(const int* p) {
  return __hip_atomic_load(p, __ATOMIC_RELAXED, __HIP_MEMORY_SCOPE_AGENT);
}

// Coherent 16B load/store: sc0 sc1 bypass L1 + per-XCD L2 (read/write the
// cross-XCD coherence point). Hazard tracking manual (s_waitcnt + sched_barrier).
#define GLD16A(dst, p, OFS) \
  asm volatile("global_load_dwordx4 %0, %1, off offset:" OFS " sc0 sc1" \
               : "=v"(dst) : "v"(p) : "memory")
#define GST16A(p, val, OFS) \
  asm volatile("global_store_dwordx4 %0, %1, off offset:" OFS " sc0 sc1" \
               :: "v"(p), "v"(val) : "memory")

// 8 named 16B registers (32 VGPRs): one K-half fragment (16 rows x 256 K).
struct Frag8 { u32x4 d0,d1,d2,d3,d4,d5,d6,d7; };

__device__ __forceinline__ void issue_frag8A(const u16* p, Frag8& f) {
  GLD16A(f.d0, p, "0");   GLD16A(f.d1, p, "64");
  GLD16A(f.d2, p, "128"); GLD16A(f.d3, p, "192");
  GLD16A(f.d4, p, "256"); GLD16A(f.d5, p, "320");
  GLD16A(f.d6, p, "384"); GLD16A(f.d7, p, "448");
}

__device__ __forceinline__ bool chk16(u32x4 q) {
  union { u32x4 q; u64 h[2]; } u; u.q = q;
  return (u.h[0] != CAN64) & (u.h[1] != CAN64);
}
__device__ __forceinline__ bool frag8_ok(const Frag8& f) {
  bool ok = chk16(f.d0);
  ok &= chk16(f.d1); ok &= chk16(f.d2); ok &= chk16(f.d3);
  ok &= chk16(f.d4); ok &= chk16(f.d5); ok &= chk16(f.d6); ok &= chk16(f.d7);
  return ok;
}

// K-half (8 chunk) MFMA chain over NT col-tiles; partials accumulated in acc[].
template <int NT>
__device__ __forceinline__ void frag_compute8(const Frag8& f, const u16 (*w)[520],
                                              int lane, int kq2, int ngr, f32x4* acc) {
#define HSTEP(ii, dd) { union { u32x4 q; bf16x8 v; } c; c.q = f.dd; \
  _Pragma("unroll") \
  for (int n2 = 0; n2 < NT; ++n2) { \
    int cw = n2 * 16 + (lane & 15); int wr2 = cw < ngr ? cw : ngr - 1; \
    bf16x8 bv = *reinterpret_cast<const bf16x8*>(&w[wr2][kq2 + ii * 32]); \
    acc[n2] = __builtin_amdgcn_mfma_f32_16x16x32_bf16(c.v, bv, acc[n2], 0, 0, 0); } }
  HSTEP(0,d0) HSTEP(1,d1) HSTEP(2,d2) HSTEP(3,d3)
  HSTEP(4,d4) HSTEP(5,d5) HSTEP(6,d6) HSTEP(7,d7)
#undef HSTEP
}

// Min of consumer-progress flags across the wave (lanes >= n contribute MAX).
__device__ __forceinline__ int poll_min(const int* base, int n, int lane) {
  int f = 0x7fffffff;
  if (lane < n) f = ld_flag(&base[lane]);
#pragma unroll
  for (int off = 32; off >= 1; off >>= 1) {
    int o = __shfl_xor(f, off);
    f = o < f ? o : f;
  }
  return f;
}

// ---------------- cast fp32 -> bf16 ----------------
__global__ __launch_bounds__(256) void cast_f32_bf16(const float* __restrict__ in,
                                                     u16* __restrict__ out, int n) {
  int i = (blockIdx.x * 256 + threadIdx.x) * 8;
  if (i + 7 < n) {
    float4 v0 = *reinterpret_cast<const float4*>(in + i);
    float4 v1 = *reinterpret_cast<const float4*>(in + i + 4);
    uint4 o;
    o.x = (unsigned)f2bf(v0.x) | ((unsigned)f2bf(v0.y) << 16);
    o.y = (unsigned)f2bf(v0.z) | ((unsigned)f2bf(v0.w) << 16);
    o.z = (unsigned)f2bf(v1.x) | ((unsigned)f2bf(v1.y) << 16);
    o.w = (unsigned)f2bf(v1.z) | ((unsigned)f2bf(v1.w) << 16);
    *reinterpret_cast<uint4*>(out + i) = o;
  } else {
    for (; i < n; ++i) out[i] = f2bf(in[i]);
  }
}

// ---------------- canary fill for the rings ----------------
__global__ __launch_bounds__(256) void fill_canary(u64* __restrict__ p, long n) {
  long i = (long)blockIdx.x * 256 + threadIdx.x;
  if (i < n) p[i] = CAN64;
}

// ---------------- LSTM input GEMM: out[t][b][k][g] = x @ w_ih^T + b_ih + b_hh ----------------
__global__ __launch_bounds__(256) void gemm_xg(
    const u16* __restrict__ A, const u16* __restrict__ W,
    const float* __restrict__ bias1, const float* __restrict__ bias2,
    u16* __restrict__ out, int N, int K, int strideB, int strideT)
{
  __shared__ u16 As[64][72];
  __shared__ u16 Bs[64][72];
  int tid  = threadIdx.x;
  int lane = tid & 63;
  int wave = tid >> 6;
  int m0 = blockIdx.x * 64;
  int n0 = blockIdx.y * 64;

  f32x4 zero = {0.f, 0.f, 0.f, 0.f};
  f32x4 acc[4] = {zero, zero, zero, zero};

  int srow = tid >> 2;
  int scol = (tid & 3) * 16;

  int m_s = m0 + srow;
  long arow = (long)(m_s & (BATCH - 1)) * strideB + (long)(m_s >> 5) * strideT;
  const u16* aptr = A + arow * K + scol;
  const u16* wptr = W + (long)(n0 + srow) * K + scol;

  for (int kk = 0; kk < K; kk += 64) {
    __syncthreads();
    uint4 a0 = *reinterpret_cast<const uint4*>(aptr + kk);
    uint4 a1 = *reinterpret_cast<const uint4*>(aptr + kk + 8);
    uint4 b0 = *reinterpret_cast<const uint4*>(wptr + kk);
    uint4 b1 = *reinterpret_cast<const uint4*>(wptr + kk + 8);
    *reinterpret_cast<uint4*>(&As[srow][scol])     = a0;
    *reinterpret_cast<uint4*>(&As[srow][scol + 8]) = a1;
    *reinterpret_cast<uint4*>(&Bs[srow][scol])     = b0;
    *reinterpret_cast<uint4*>(&Bs[srow][scol + 8]) = b1;
    __syncthreads();
    int am = wave * 16 + (lane & 15);
    int kq = (lane >> 4) * 8;
#pragma unroll
    for (int ks = 0; ks < 2; ++ks) {
      bf16x8 af = *reinterpret_cast<const bf16x8*>(&As[am][kq + ks * 32]);
#pragma unroll
      for (int nb = 0; nb < 4; ++nb) {
        bf16x8 bf = *reinterpret_cast<const bf16x8*>(&Bs[nb * 16 + (lane & 15)][kq + ks * 32]);
        acc[nb] = __builtin_amdgcn_mfma_f32_16x16x32_bf16(af, bf, acc[nb], 0, 0, 0);
      }
    }
  }
  int quad = lane >> 4;
#pragma unroll
  for (int nb = 0; nb < 4; ++nb) {
    int n = n0 + nb * 16 + (lane & 15);
    float bv = bias1[n] + (bias2 ? bias2[n] : 0.0f);
    int g = n >> 9, k = n & 511;
#pragma unroll
    for (int r = 0; r < 4; ++r) {
      int m = m0 + wave * 16 + quad * 4 + r;
      int t = m >> 5, b = m & (BATCH - 1);
      out[(((long)t * BATCH + b) * HID + k) * 4 + g] = f2bf(acc[nb][r] + bv);
    }
  }
}

// ---------------- persistent recurrent role (ROLE: 0=LSTM 1=GRU 2=RNN) ----------------
// Canary protocol (round-2 semantics). New in this round:
//  * K-split gathers: wave (mt,kh) loads rows [mt*16,+16) x K-half [kh*256,+256)
//    (8 KB, no duplication) and computes PARTIAL sums for all NT col-tiles.
//    Partials combined in LDS: kh0 writes, barrier, kh1 adds, barrier, cell.
//  * fX (upstream) prefetched one step ahead; canary-validated at use. When we
//    are at step t the upstream has finished step t, so its slot t+1 is already
//    re-canaried or newer -> stale-accept impossible; torn/canary -> retry.
//  * publish-side vmcnt(0) removed (retry-loop vmcnt orders canary-before-data;
//    keeping it would stall the publish on in-flight prefetch loads).
template <int ROLE>
__device__ void recur_role(
    int wg, const u16* __restrict__ xg, const u16* __restrict__ up,
    const u16* __restrict__ wih, const u16* __restrict__ whh,
    const float* __restrict__ bih, const float* __restrict__ bhh,
    u16* __restrict__ hist, int* fl_own,
    const int* cons, int n_cons,
    u16 (*w_lds)[520], float (*gx)[33], float (*gh)[33], u16 (*hs)[8])
{
  constexpr int NG   = (ROLE == 0) ? 4 : (ROLE == 1) ? 3 : 1;
  constexpr int NGR  = NG * 8;
  constexpr int XROWS = (ROLE > 0) ? NGR : 0;   // x-weight rows staged
  constexpr int TOT  = XROWS + NGR;
  constexpr int NT   = (ROLE == 2) ? 1 : 2;     // col-tiles covering NGR outputs
  constexpr bool HASX = (ROLE > 0);
  int tid = threadIdx.x, lane = tid & 63, wave = tid >> 6;
  int hbase = wg * 8;

  // stage weights compactly: rows [0,XROWS) = w_ih slice, [XROWS,TOT) = w_hh slice
  for (int idx = tid; idx < TOT * 64; idx += 256) {
    int row = idx >> 6, chunk = idx & 63;
    int n = (row < XROWS) ? row : (row - XROWS);
    const u16* src = (row < XROWS) ? wih : whh;
    int g = n >> 3, dd = n & 7;
    uint4 v = *reinterpret_cast<const uint4*>(src + ((long)(g * 512 + hbase + dd)) * 512 + chunk * 8);
    *reinterpret_cast<uint4*>(&w_lds[row][chunk * 8]) = v;
  }
  __syncthreads();

  int mt = wave & 1, kh = wave >> 1;            // m-tile / K-half split
  int arow = mt * 16 + (lane & 15);
  int kq2  = kh * 256 + (lane >> 4) * 8;        // per-lane K base within the half
  int quad = lane >> 4;
  int b_c = tid >> 3, d_c = tid & 7;            // cell thread owns h[b_c][hbase+d_c]
  float c_st = 0.f, h_st = 0.f;
  int ccache = 0;                               // cached min of consumer progress
  float bx0 = 0.f, bx1 = 0.f, bx2 = 0.f, bh0 = 0.f, bh1 = 0.f, bh2 = 0.f;
  if constexpr (ROLE == 1) {
    bx0 = bih[0 * 512 + hbase + d_c]; bx1 = bih[1 * 512 + hbase + d_c]; bx2 = bih[2 * 512 + hbase + d_c];
    bh0 = bhh[0 * 512 + hbase + d_c]; bh1 = bhh[1 * 512 + hbase + d_c]; bh2 = bhh[2 * 512 + hbase + d_c];
  }
  if constexpr (ROLE == 2) bx0 = bih[hbase + d_c] + bhh[hbase + d_c];

  Frag8 fXn;
  if constexpr (HASX)   // prologue prefetch of upstream slot 0
    issue_frag8A(up + ((long)0 * BATCH + arow) * HID + kq2, fXn);

  for (int t = 0; t < T_SEQ; ++t) {
    u64 xq = 0;
    if constexpr (ROLE == 0)
      xq = *reinterpret_cast<const u64*>(xg + (((long)t * BATCH + b_c) * HID + hbase + d_c) * 4);

    // wave0: amortized downstream gate + re-canary own ring slot t+1
    if (wave == 0) {
      if (cons != nullptr && t >= RING - 1) {
        int need = t - (RING - 2);
        while (ccache < need) {
          ccache = poll_min(cons, n_cons, lane);
          if (ccache < need) __builtin_amdgcn_s_sleep(8);
        }
      }
      int pb = lane >> 1, half = lane & 1;
      st_dev(reinterpret_cast<u64*>(
                 hist + (((long)((t + 1) & (RING - 1)) * BATCH + pb) * HID + hbase + half * 4)),
             CAN64);
    }

    f32x4 zero4 = {0.f, 0.f, 0.f, 0.f};
    f32x4 aXp[NT], aHp[NT];
#pragma unroll
    for (int n2 = 0; n2 < NT; ++n2) { aXp[n2] = zero4; aHp[n2] = zero4; }

    // --- fH retry (recurrence critical path: detect + load combined) ---
    Frag8 fH;
    if (t > 0) {
      const u16* pH = hist + ((long)((t - 1) & (RING - 1)) * BATCH + arow) * HID + kq2;
      while (true) {
        issue_frag8A(pH, fH);
        asm volatile("s_waitcnt vmcnt(0)" ::: "memory");
        __builtin_amdgcn_sched_barrier(0);
        if (__all(frag8_ok(fH))) break;
        __builtin_amdgcn_s_sleep(1);
      }
    } else {
      // drain prologue prefetch + wave0 canary stores
      asm volatile("s_waitcnt vmcnt(0)" ::: "memory");
      __builtin_amdgcn_sched_barrier(0);
    }

    // --- fX: validate prefetched fragment, compute, then prefetch t+1 ---
    if constexpr (HASX) {
      const u16* pX = up + ((long)(t & (RING - 1)) * BATCH + arow) * HID + kq2;
      bool ok = (bool)__all(frag8_ok(fXn));
      while (!ok) {
        issue_frag8A(pX, fXn);
        asm volatile("s_waitcnt vmcnt(0)" ::: "memory");
        __builtin_amdgcn_sched_barrier(0);
        ok = (bool)__all(frag8_ok(fXn));
        if (!ok) __builtin_amdgcn_s_sleep(1);
      }
      frag_compute8<NT>(fXn, w_lds, lane, kq2, NGR, aXp);
      __builtin_amdgcn_sched_barrier(0);
      if (t + 1 < T_SEQ)
        issue_frag8A(up + ((long)((t + 1) & (RING - 1)) * BATCH + arow) * HID + kq2, fXn);
    }
    if (t > 0)
      frag_compute8<NT>(fH, w_lds + XROWS, lane, kq2, NGR, aHp);

    // --- combine K-half partials in LDS: kh0 writes, kh1 adds ---
    if (kh == 0) {
#pragma unroll
      for (int n2 = 0; n2 < NT; ++n2)
#pragma unroll
        for (int r = 0; r < 4; ++r) {
          int row = mt * 16 + quad * 4 + r, col = n2 * 16 + (lane & 15);
          if constexpr (HASX) gx[row][col] = aXp[n2][r];
          gh[row][col] = aHp[n2][r];
        }
    }
    __syncthreads();
    if (kh == 1) {
#pragma unroll
      for (int n2 = 0; n2 < NT; ++n2)
#pragma unroll
        for (int r = 0; r < 4; ++r) {
          int row = mt * 16 + quad * 4 + r, col = n2 * 16 + (lane & 15);
          if constexpr (HASX) gx[row][col] += aXp[n2][r];
          gh[row][col] += aHp[n2][r];
        }
    }
    __syncthreads();

    // --- cell ---
    float hnew;
    if constexpr (ROLE == 0) {
      float xv0 = bf2f((u16)(xq));
      float xv1 = bf2f((u16)(xq >> 16));
      float xv2 = bf2f((u16)(xq >> 32));
      float xv3 = bf2f((u16)(xq >> 48));
      float h0 = gh[b_c][0 * 8 + d_c];
      float h1 = gh[b_c][1 * 8 + d_c];
      float h2 = gh[b_c][2 * 8 + d_c];
      float h3 = gh[b_c][3 * 8 + d_c];
      float ig = sigf(xv0 + h0), fg = sigf(xv1 + h1);
      float gg = tanh_fast(xv2 + h2), og = sigf(xv3 + h3);
      c_st = fg * c_st + ig * gg;
      hnew = og * tanh_fast(c_st);
    } else if constexpr (ROLE == 1) {
      float xr_ = gx[b_c][0 * 8 + d_c] + bx0;
      float xz  = gx[b_c][1 * 8 + d_c] + bx1;
      float xn  = gx[b_c][2 * 8 + d_c] + bx2;
      float hr  = gh[b_c][0 * 8 + d_c] + bh0;
      float hz  = gh[b_c][1 * 8 + d_c] + bh1;
      float hn  = gh[b_c][2 * 8 + d_c] + bh2;
      float r = sigf(xr_ + hr), z = sigf(xz + hz);
      float n = tanh_fast(xn + r * hn);
      hnew = (1.f - z) * n + z * h_st;
      h_st = hnew;
    } else {
      hnew = tanh_fast(gx[b_c][d_c] + bx0 + gh[b_c][d_c]);
    }
    hs[b_c][d_c] = f2bf(hnew);
    __syncthreads();

    // --- publish (fire-and-forget; canary(t+1) already committed before now) ---
    if (wave == 0) {
      int pb = lane >> 1, half = lane & 1;
      u64 val = *reinterpret_cast<const u64*>(&hs[pb][half * 4]);
      st_dev(reinterpret_cast<u64*>(
                 hist + (((long)(t & (RING - 1)) * BATCH + pb) * HID + hbase + half * 4)),
             val);
      if (tid == 0 && fl_own != nullptr)
        st_tag(&fl_own[wg], t + 1);
    }
  }
}

// ---------------- pipelined LayerNorm role (4 WGs x 8 rows) ----------------
__device__ void ln_role(int wg, const u16* __restrict__ in, u16* __restrict__ out,
                        const float* __restrict__ gv, const float* __restrict__ bv,
                        int* fl_out, const int* cons, int n_cons)
{
  int tid = threadIdx.x, lane = tid & 63, wave = tid >> 6;
  int row = wg * 8 + wave * 2 + (lane >> 5);
  int l32 = lane & 31, k0 = l32 * 16;
  float gr[16], br[16];
#pragma unroll
  for (int j = 0; j < 16; ++j) { gr[j] = gv[k0 + j]; br[j] = bv[k0 + j]; }
  int ccache = 0;
  u32x4 canv = {0x7FC07FC0u, 0x7FC07FC0u, 0x7FC07FC0u, 0x7FC07FC0u};

  for (int t = 0; t < T_SEQ; ++t) {
    // gate (amortized) + re-canary out slot t+1 (drained by retry vmcnt below)
    if (t >= RING - 1) {
      int need = t - (RING - 2);
      while (ccache < need) {
        ccache = poll_min(cons, n_cons, lane);
        if (ccache < need) __builtin_amdgcn_s_sleep(8);
      }
    }
    u16* pc = out + ((long)((t + 1) & (RING - 1)) * BATCH + row) * HID + k0;
    GST16A(pc, canv, "0");
    GST16A(pc, canv, "16");

    const u16* p = in + ((long)(t & (RING - 1)) * BATCH + row) * HID + k0;
    u32x4 q0, q1;
    bool ok;
    do {
      GLD16A(q0, p, "0");
      GLD16A(q1, p, "16");
      asm volatile("s_waitcnt vmcnt(0)" ::: "memory");
      __builtin_amdgcn_sched_barrier(0);
      ok = (bool)__all(chk16(q0) & chk16(q1));
    } while (!ok);

    union { u32x4 q; u16 s[8]; } u0, u1;
    u0.q = q0; u1.q = q1;
    float x[16];
#pragma unroll
    for (int i = 0; i < 8; ++i) { x[i] = bf2f(u0.s[i]); x[8 + i] = bf2f(u1.s[i]); }
    float s = 0.f, s2 = 0.f;
#pragma unroll
    for (int i = 0; i < 16; ++i) { s += x[i]; s2 += x[i] * x[i]; }
#pragma unroll
    for (int off = 1; off < 32; off <<= 1) { s += __shfl_xor(s, off); s2 += __shfl_xor(s2, off); }
    float mu = s * (1.f / 512.f);
    float var = s2 * (1.f / 512.f) - mu * mu;
    float rs = rsqrtf(var + 1e-5f);
    union { u16 o[16]; u32x4 q[2]; } ov;
#pragma unroll
    for (int i = 0; i < 16; ++i) ov.o[i] = f2bf((x[i] - mu) * rs * gr[i] + br[i]);
    u16* po = out + ((long)(t & (RING - 1)) * BATCH + row) * HID + k0;
    GST16A(po, ov.q[0], "0");
    GST16A(po, ov.q[1], "16");
    __syncthreads();
    if (tid == 0) st_tag(&fl_out[wg], t + 1);
  }
}

// ---------------- fused pipeline kernel: 200 WGs ----------------
// progress flags (back-pressure only): [64..67] ln1, [128..191] gru,
// [192..195] ln2, [256..319] rnn
__global__ __launch_bounds__(256, 1) void fused_kernel(
    const u16* __restrict__ xg, const u16* __restrict__ lstm_whh,
    const u16* __restrict__ gru_wih, const u16* __restrict__ gru_whh,
    const float* __restrict__ gru_bih, const float* __restrict__ gru_bhh,
    const u16* __restrict__ rnn_wih, const u16* __restrict__ rnn_whh,
    const float* __restrict__ rnn_bih, const float* __restrict__ rnn_bhh,
    const float* __restrict__ ln1_g, const float* __restrict__ ln1_b,
    const float* __restrict__ ln2_g, const float* __restrict__ ln2_b,
    u16* h1, u16* ln1o, u16* h2, u16* ln2o, u16* h3, int* fl)
{
  __shared__ u16 w_lds[48][520];     // 49.9 KB  (total static LDS 58.9 KB < 64 KB)
  __shared__ float gx[32][33];       // 4.2 KB
  __shared__ float gh[32][33];       // 4.2 KB
  __shared__ u16 hs[32][8];          // 0.5 KB
  int bid = blockIdx.x;
  if (bid < 64)
    recur_role<0>(bid, xg, nullptr, nullptr, lstm_whh, nullptr, nullptr,
                  h1, nullptr, fl + 64, 4, w_lds, gx, gh, hs);
  else if (bid < 68)
    ln_role(bid - 64, h1, ln1o, ln1_g, ln1_b, fl + 64, fl + 128, 64);
  else if (bid < 132)
    recur_role<1>(bid - 68, nullptr, ln1o, gru_wih, gru_whh, gru_bih, gru_bhh,
                  h2, fl + 128, fl + 192, 4, w_lds, gx, gh, hs);
  else if (bid < 136)
    ln_role(bid - 132, h2, ln2o, ln2_g, ln2_b, fl + 192, fl + 256, 64);
  else
    recur_role<2>(bid - 136, nullptr, ln2o, rnn_wih, rnn_whh, rnn_bih, rnn_bhh,
                  h3, fl + 256, nullptr, 0, w_lds, gx, gh, hs);
}

// ---------------- final FC ----------------
__global__ __launch_bounds__(256) void fc_kernel(
    const u16* __restrict__ hlast, const u16* __restrict__ w,
    const float* __restrict__ bias, float* __restrict__ out)
{
  int tg = blockIdx.x * 256 + threadIdx.x;
  if (tg >= BATCH * 1000) return;
  int b = tg / 1000, o = tg % 1000;
  const u16* hp = hlast + (long)b * HID;
  const u16* wp = w + (long)o * HID;
  float acc = 0.f;
  for (int k = 0; k < HID; k += 8) {
    uint4 hu = *reinterpret_cast<const uint4*>(hp + k);
    uint4 wu = *reinterpret_cast<const uint4*>(wp + k);
    u16* hsv = reinterpret_cast<u16*>(&hu);
    u16* wsv = reinterpret_cast<u16*>(&wu);
#pragma unroll
    for (int i = 0; i < 8; ++i) acc += bf2f(hsv[i]) * bf2f(wsv[i]);
  }
  out[tg] = acc + bias[o];
}

__global__ void sentinel_kernel(float* out) { out[0] = 12345.0f; }

// ---------------- launch ----------------
extern "C" void kernel_launch(void* const* d_in, const int* in_sizes, int n_in,
                              void* d_out, int out_size, void* d_ws, size_t ws_size,
                              hipStream_t stream)
{
  (void)in_sizes; (void)n_in; (void)out_size;
  const float* x        = (const float*)d_in[0];
  const float* lstm_wih = (const float*)d_in[1];
  const float* lstm_whh = (const float*)d_in[2];
  const float* lstm_bih = (const float*)d_in[3];
  const float* lstm_bhh = (const float*)d_in[4];
  const float* ln1_g    = (const float*)d_in[5];
  const float* ln1_b    = (const float*)d_in[6];
  const float* gru_wih  = (const float*)d_in[7];
  const float* gru_whh  = (const float*)d_in[8];
  const float* gru_bih  = (const float*)d_in[9];
  const float* gru_bhh  = (const float*)d_in[10];
  const float* ln2_g    = (const float*)d_in[11];
  const float* ln2_b    = (const float*)d_in[12];
  const float* rnn_wih  = (const float*)d_in[13];
  const float* rnn_whh  = (const float*)d_in[14];
  const float* rnn_bih  = (const float*)d_in[15];
  const float* rnn_bhh  = (const float*)d_in[16];
  const float* fc_w     = (const float*)d_in[17];
  const float* fc_b     = (const float*)d_in[18];
  float* out = (float*)d_out;

  char* ws = (char*)d_ws;
  size_t off = 0;
  auto alloc = [&](size_t bytes) -> void* {
    void* p = ws + off; off += (bytes + 255) & ~(size_t)255; return p;
  };
  int* flags     = (int*)alloc(320 * sizeof(int));
  u16* xbf       = (u16*)alloc((size_t)BATCH * T_SEQ * 256 * 2);
  u16* lstm_wih_b= (u16*)alloc((size_t)2048 * 256 * 2);
  u16* lstm_whh_b= (u16*)alloc((size_t)2048 * 512 * 2);
  u16* gru_wih_b = (u16*)alloc((size_t)1536 * 512 * 2);
  u16* gru_whh_b = (u16*)alloc((size_t)1536 * 512 * 2);
  u16* rnn_wih_b = (u16*)alloc((size_t)512 * 512 * 2);
  u16* rnn_whh_b = (u16*)alloc((size_t)512 * 512 * 2);
  u16* fc_w_b    = (u16*)alloc((size_t)1000 * 512 * 2);
  u16* xg2       = (u16*)alloc((size_t)T_SEQ * BATCH * HID * 4 * 2);  // 128 MB
  // 5 contiguous 1 MB rings (each size % 256 == 0 -> no padding between)
  u16* h1        = (u16*)alloc((size_t)RING * BATCH * HID * 2);
  u16* ln1o      = (u16*)alloc((size_t)RING * BATCH * HID * 2);
  u16* h2        = (u16*)alloc((size_t)RING * BATCH * HID * 2);
  u16* ln2o      = (u16*)alloc((size_t)RING * BATCH * HID * 2);
  u16* h3        = (u16*)alloc((size_t)RING * BATCH * HID * 2);

  if (off > ws_size) {
    sentinel_kernel<<<1, 1, 0, stream>>>(out);
    return;
  }

  hipMemsetAsync(flags, 0, 320 * sizeof(int), stream);

  // pre-fill all rings with the canary pattern
  const long ncan = 5L * RING * BATCH * HID * 2 / 8;   // u64 count over 5 rings
  fill_canary<<<(int)((ncan + 255) / 256), 256, 0, stream>>>((u64*)h1, ncan);

  auto cast = [&](const float* src, u16* dst, int n) {
    cast_f32_bf16<<<(n + 2047) / 2048, 256, 0, stream>>>(src, dst, n);
  };
  cast(x,        xbf,        BATCH * T_SEQ * 256);
  cast(lstm_wih, lstm_wih_b, 2048 * 256);
  cast(lstm_whh, lstm_whh_b, 2048 * 512);
  cast(gru_wih,  gru_wih_b,  1536 * 512);
  cast(gru_whh,  gru_whh_b,  1536 * 512);
  cast(rnn_wih,  rnn_wih_b,  512 * 512);
  cast(rnn_whh,  rnn_whh_b,  512 * 512);
  cast(fc_w,     fc_w_b,     1000 * 512);

  const int M64 = (BATCH * T_SEQ) / 64;  // 512
  gemm_xg<<<dim3(M64, 2048 / 64), 256, 0, stream>>>(
      xbf, lstm_wih_b, lstm_bih, lstm_bhh, xg2, 2048, 256, 1024, 1);

  fused_kernel<<<200, 256, 0, stream>>>(
      xg2, lstm_whh_b,
      gru_wih_b, gru_whh_b, gru_bih, gru_bhh,
      rnn_wih_b, rnn_whh_b, rnn_bih, rnn_bhh,
      ln1_g, ln1_b, ln2_g, ln2_b,
      h1, ln1o, h2, ln2o, h3, flags);

  // h3 last written slot = (T_SEQ-1)&31 = 31
  fc_kernel<<<(BATCH * 1000 + 255) / 256, 256, 0, stream>>>(
      h3 + (size_t)31 * BATCH * HID, fc_w_b, fc_b, out);
}